// Round 6
// baseline (94.562 us; speedup 1.0000x reference)
//
#include <hip/hip_runtime.h>
#include <math.h>

// Problem shape (fixed by the reference): B=4, S=4, N=2048, D=2048
#define NB 4
#define NS 4
#define NN 2048
#define ND 2048
#define NTHREADS 256
#define SQRT_D 45.254833995939045f   // sqrt(2048)

typedef float f32x4 __attribute__((ext_vector_type(4)));

#if __has_builtin(__builtin_amdgcn_global_load_lds)
#define HAVE_DMA 1
typedef __attribute__((address_space(3))) void lds_void_t;
typedef const __attribute__((address_space(1))) void glb_void_t;
// global src is PER-LANE, LDS dest is wave-uniform base + lane*16 (R5-verified)
#define ASYNC_COPY16(g, l) \
    __builtin_amdgcn_global_load_lds((glb_void_t*)(g), (lds_void_t*)(l), 16, 0, 0)
#else
#define HAVE_DMA 0
#endif

// Compaction-butterfly ship, literal indices only (R3 lesson).
#define SHIP(I, H, M_) {                                      \
    const float keep_ = hi_ ? v[(I)+(H)] : v[(I)];            \
    const float give_ = hi_ ? v[(I)] : v[(I)+(H)];            \
    v[(I)] = keep_ + __shfl_xor(give_, (M_)); }

__global__ __launch_bounds__(NTHREADS, 4)
void hyperconn_kernel(const float* __restrict__ residuals,
                      const float* __restrict__ gamma,
                      const float* __restrict__ w_alpha,
                      const float* __restrict__ scale_alpha,
                      const float* __restrict__ static_alpha,
                      const float* __restrict__ w_beta,
                      const float* __restrict__ scale_beta,
                      const float* __restrict__ static_beta,
                      float* __restrict__ out)
{
    __shared__ float lds_x[NS * ND];   // 32 KB: 4 input rows, linear
    __shared__ float red[4][32];       // per-wave compacted sums (idx = brev5)

    const int tid  = threadIdx.x;
    const int bn   = blockIdx.x;          // 0 .. NB*NN-1
    const int b    = bn >> 11;
    const int n    = bn & (NN - 1);
    const int wave = tid >> 6;
    const int lane = tid & 63;
    // Wave w owns d-slice [w*512, (w+1)*512) of ALL rows: it stages exactly
    // what it later reads -> no block-wide rendezvous for staging.
    const int d0   = (wave << 9) + (lane << 2);
    const int d1   = d0 + 256;

    const size_t row_stride = (size_t)NN * ND;
    const float* xbase = residuals + (size_t)(b * NS) * row_stride + (size_t)n * ND;

    // Per-lane epilogue constants, issued before the vmcnt drain below.
    const int l24 = (lane < 24) ? lane : 0;
    const int es = l24 / 6, ej = l24 % 6;
    const float sa = scale_alpha[0], sb = scale_beta[0];
    const float stat = (ej < 5) ? static_alpha[es * 5 + ej] : static_beta[es];

    // ---- Stage own slice of the 4 rows (8 KB/wave, 8 DMA issues) ----
#if HAVE_DMA
#pragma unroll
    for (int s = 0; s < NS; ++s) {
        const float* g = xbase + (size_t)s * row_stride + (wave << 9) + (lane << 2);
        ASYNC_COPY16(g,       &lds_x[s * ND + (wave << 9)]);
        ASYNC_COPY16(g + 256, &lds_x[s * ND + (wave << 9) + 256]);
    }
#else
    {
        f32x4 t[8];
#pragma unroll
        for (int s = 0; s < NS; ++s) {
            const float* g = xbase + (size_t)s * row_stride + (wave << 9) + (lane << 2);
            t[s * 2 + 0] = *(const f32x4*)(g);
            t[s * 2 + 1] = *(const f32x4*)(g + 256);
        }
#pragma unroll
        for (int s = 0; s < NS; ++s) {
            *(f32x4*)&lds_x[s * ND + d0] = t[s * 2 + 0];
            *(f32x4*)&lds_x[s * ND + d1] = t[s * 2 + 1];
        }
    }
#endif
    // Per-wave drain of our own DMA (no __syncthreads): ds_reads below may
    // not be hoisted above this (memory clobber orders them).
    asm volatile("s_waitcnt vmcnt(0)" ::: "memory");

    // ---- Dots on own slice: v[s*7]=ssq; v[s*7+1+j]=dot(x, w_j*(1+g)) ----
    float v[32];
#pragma unroll
    for (int k = 0; k < 32; ++k) v[k] = 0.f;

#pragma unroll
    for (int c = 0; c < 2; ++c) {
        const int d = (c == 0) ? d0 : d1;
        f32x4 g4 = *(const f32x4*)(gamma + d);
        f32x4 wg[6];
#pragma unroll
        for (int j = 0; j < 6; ++j) {
            const float* wsrc = (j < 5) ? (w_alpha + (size_t)j * ND + d) : (w_beta + d);
            f32x4 w4 = *(const f32x4*)wsrc;
            wg[j] = w4 + w4 * g4;          // w * (1 + gamma)
        }
#pragma unroll
        for (int s = 0; s < NS; ++s) {
            f32x4 xs = *(const f32x4*)&lds_x[s * ND + d];
#pragma unroll
            for (int e = 0; e < 4; ++e) {
                v[s * 7 + 0] = __builtin_fmaf(xs[e], xs[e], v[s * 7 + 0]);
#pragma unroll
                for (int j = 0; j < 6; ++j)
                    v[s * 7 + 1 + j] = __builtin_fmaf(xs[e], wg[j][e], v[s * 7 + 1 + j]);
            }
        }
    }

    // ---- Compaction butterfly: 31 swizzles + 1 xor32 (R5-proven) ----
    { const bool hi_ = (lane & 1) != 0;
      SHIP(0,16,1)  SHIP(1,16,1)  SHIP(2,16,1)  SHIP(3,16,1)
      SHIP(4,16,1)  SHIP(5,16,1)  SHIP(6,16,1)  SHIP(7,16,1)
      SHIP(8,16,1)  SHIP(9,16,1)  SHIP(10,16,1) SHIP(11,16,1)
      SHIP(12,16,1) SHIP(13,16,1) SHIP(14,16,1) SHIP(15,16,1) }
    { const bool hi_ = (lane & 2) != 0;
      SHIP(0,8,2) SHIP(1,8,2) SHIP(2,8,2) SHIP(3,8,2)
      SHIP(4,8,2) SHIP(5,8,2) SHIP(6,8,2) SHIP(7,8,2) }
    { const bool hi_ = (lane & 4) != 0;
      SHIP(0,4,4) SHIP(1,4,4) SHIP(2,4,4) SHIP(3,4,4) }
    { const bool hi_ = (lane & 8) != 0;
      SHIP(0,2,8) SHIP(1,2,8) }
    { const bool hi_ = (lane & 16) != 0;
      SHIP(0,1,16) }
    const float tot = v[0] + __shfl_xor(v[0], 32);
    const int idx = ((lane & 1) << 4) | ((lane & 2) << 2) | (lane & 4)
                  | ((lane & 8) >> 2) | ((lane & 16) >> 4);   // brev5(lane&31)
    if (lane < 32) red[wave][idx] = tot;
    __syncthreads();   // the ONLY block-wide sync

    // ---- Per-wave epilogue: lane l<24 computes one tanh; M via shfl (R4-proven) ----
    const float ssq = red[0][es * 7] + red[1][es * 7] + red[2][es * 7] + red[3][es * 7];
    const int  di  = es * 7 + 1 + ej;
    const float dt  = red[0][di] + red[1][di] + red[2][di] + red[3][di];
    const float rs  = SQRT_D / fmaxf(sqrtf(ssq), 1e-12f);
    const float aval = __builtin_fmaf(tanhf(dt * rs), (ej < 5) ? sa : sb, stat);

    float a0[4];
#pragma unroll
    for (int si = 0; si < 4; ++si) a0[si] = __shfl(aval, si * 6);
    float M[4][4];
#pragma unroll
    for (int so = 0; so < 4; ++so) {
        const float bso = __shfl(aval, so * 6 + 5);
#pragma unroll
        for (int si = 0; si < 4; ++si)
            M[so][si] = __builtin_fmaf(bso, a0[si], __shfl(aval, si * 6 + so + 1));
    }

    // ---- Apply on own slice: out[so][d] = sum_si M[so][si]*x[si][d] ----
    float* obase = out + (size_t)(b * NS) * row_stride + (size_t)n * ND;
#pragma unroll
    for (int c = 0; c < 2; ++c) {
        const int d = (c == 0) ? d0 : d1;
        f32x4 xs0 = *(const f32x4*)&lds_x[0 * ND + d];
        f32x4 xs1 = *(const f32x4*)&lds_x[1 * ND + d];
        f32x4 xs2 = *(const f32x4*)&lds_x[2 * ND + d];
        f32x4 xs3 = *(const f32x4*)&lds_x[3 * ND + d];
#pragma unroll
        for (int so = 0; so < 4; ++so) {
            f32x4 o;
#pragma unroll
            for (int e = 0; e < 4; ++e)
                o[e] = M[so][0] * xs0[e] + M[so][1] * xs1[e]
                     + M[so][2] * xs2[e] + M[so][3] * xs3[e];
            __builtin_nontemporal_store(o, (f32x4*)(obase + (size_t)so * row_stride + d));
        }
    }
}

extern "C" void kernel_launch(void* const* d_in, const int* in_sizes, int n_in,
                              void* d_out, int out_size, void* d_ws, size_t ws_size,
                              hipStream_t stream) {
    const float* residuals    = (const float*)d_in[0];
    const float* gamma        = (const float*)d_in[1];
    const float* w_alpha      = (const float*)d_in[2];
    const float* scale_alpha  = (const float*)d_in[3];
    const float* static_alpha = (const float*)d_in[4];
    const float* w_beta       = (const float*)d_in[5];
    const float* scale_beta   = (const float*)d_in[6];
    const float* static_beta  = (const float*)d_in[7];
    float* out = (float*)d_out;

    const int grid = NB * NN;  // 8192 blocks, one per (b, n)
    hyperconn_kernel<<<grid, NTHREADS, 0, stream>>>(
        residuals, gamma, w_alpha, scale_alpha, static_alpha,
        w_beta, scale_beta, static_beta, out);
}

// Round 7
// 84.600 us; speedup vs baseline: 1.1178x; 1.1178x over previous
//
#include <hip/hip_runtime.h>
#include <math.h>

// Problem shape (fixed by the reference): B=4, S=4, N=2048, D=2048
#define NB 4
#define NS 4
#define NN 2048
#define ND 2048
#define NTHREADS 256
#define SQRT_D 45.254833995939045f   // sqrt(2048)

typedef float f32x4 __attribute__((ext_vector_type(4)));

// RNE pack of two f32 into one dword of 2x bf16 (low = first arg). m240 recipe.
#define CVTPK(dst, a, b) \
    asm("v_cvt_pk_bf16_f32 %0, %1, %2" : "=v"(dst) : "v"(a), "v"(b))

static __device__ __forceinline__ float bflo(unsigned int u) {
    unsigned int t = u << 16; float f; __builtin_memcpy(&f, &t, 4); return f;
}
static __device__ __forceinline__ float bfhi(unsigned int u) {
    unsigned int t = u & 0xFFFF0000u; float f; __builtin_memcpy(&f, &t, 4); return f;
}

// Compaction-butterfly ship, literal indices only (R3 lesson, R5-proven).
#define SHIP(I, H, M_) {                                      \
    const float keep_ = hi_ ? v[(I)+(H)] : v[(I)];            \
    const float give_ = hi_ ? v[(I)] : v[(I)+(H)];            \
    v[(I)] = keep_ + __shfl_xor(give_, (M_)); }

// One d-chunk: load 4 rows' f32x4 from global, fma dots in fp32 from the
// LOAD REGISTERS (LDS never on the dots path), pack bf16 copy into LDS for
// the apply phase. All array indices literal.
#define CHUNK(DARG)                                                          \
  {                                                                          \
    const int d_ = (DARG);                                                   \
    const float* xp_ = xbase + d_;                                           \
    f32x4 x0 = *(const f32x4*)(xp_);                                         \
    f32x4 x1 = *(const f32x4*)(xp_ + row_stride);                            \
    f32x4 x2 = *(const f32x4*)(xp_ + 2 * row_stride);                        \
    f32x4 x3 = *(const f32x4*)(xp_ + 3 * row_stride);                        \
    f32x4 g4 = *(const f32x4*)(gamma + d_);                                  \
    _Pragma("unroll") for (int e = 0; e < 4; ++e) {                          \
        v[0]  = __builtin_fmaf(x0[e], x0[e], v[0]);                          \
        v[7]  = __builtin_fmaf(x1[e], x1[e], v[7]);                          \
        v[14] = __builtin_fmaf(x2[e], x2[e], v[14]);                         \
        v[21] = __builtin_fmaf(x3[e], x3[e], v[21]);                         \
    }                                                                        \
    {                                                                        \
        unsigned int pa, pb;                                                 \
        CVTPK(pa, x0[0], x0[1]); CVTPK(pb, x0[2], x0[3]);                    \
        *(uint2*)&lds_h[0 * ND + d_] = make_uint2(pa, pb);                   \
        CVTPK(pa, x1[0], x1[1]); CVTPK(pb, x1[2], x1[3]);                    \
        *(uint2*)&lds_h[1 * ND + d_] = make_uint2(pa, pb);                   \
        CVTPK(pa, x2[0], x2[1]); CVTPK(pb, x2[2], x2[3]);                    \
        *(uint2*)&lds_h[2 * ND + d_] = make_uint2(pa, pb);                   \
        CVTPK(pa, x3[0], x3[1]); CVTPK(pb, x3[2], x3[3]);                    \
        *(uint2*)&lds_h[3 * ND + d_] = make_uint2(pa, pb);                   \
    }                                                                        \
    _Pragma("unroll") for (int j = 0; j < 6; ++j) {                          \
        const float* wsrc = (j < 5) ? (w_alpha + (size_t)j * ND + d_)        \
                                    : (w_beta + d_);                         \
        f32x4 w4 = *(const f32x4*)wsrc;                                      \
        f32x4 wg = w4 + w4 * g4;        /* w * (1 + gamma) */                \
        _Pragma("unroll") for (int e = 0; e < 4; ++e) {                      \
            v[1 + j]  = __builtin_fmaf(x0[e], wg[e], v[1 + j]);              \
            v[8 + j]  = __builtin_fmaf(x1[e], wg[e], v[8 + j]);              \
            v[15 + j] = __builtin_fmaf(x2[e], wg[e], v[15 + j]);             \
            v[22 + j] = __builtin_fmaf(x3[e], wg[e], v[22 + j]);             \
        }                                                                    \
    }                                                                        \
  }

__global__ __launch_bounds__(NTHREADS, 4)
void hyperconn_kernel(const float* __restrict__ residuals,
                      const float* __restrict__ gamma,
                      const float* __restrict__ w_alpha,
                      const float* __restrict__ scale_alpha,
                      const float* __restrict__ static_alpha,
                      const float* __restrict__ w_beta,
                      const float* __restrict__ scale_beta,
                      const float* __restrict__ static_beta,
                      float* __restrict__ out)
{
    __shared__ unsigned short lds_h[NS * ND];  // 16 KB: bf16 copy of x (apply only)
    __shared__ float red[4][32];               // per-wave compacted sums
    __shared__ float asb[NS][6];               // [s][0..4]=alpha, [s][5]=beta

    const int tid  = threadIdx.x;
    const int bn   = blockIdx.x;          // 0 .. NB*NN-1
    const int b    = bn >> 11;
    const int n    = bn & (NN - 1);
    const int wave = tid >> 6;
    const int lane = tid & 63;
    const int d0   = tid << 2;            // [0, 1024)
    const int d1   = d0 + (ND >> 1);      // [1024, 2048)

    const size_t row_stride = (size_t)NN * ND;
    const float* xbase = residuals + (size_t)(b * NS) * row_stride + (size_t)n * ND;

    // ---- Dots in fp32 straight from global-load registers ----
    // v[s*7]=ssq(x[s]); v[s*7+1+j]=dot(x[s], w_j*(1+g)); v[28..31] pad
    float v[32];
#pragma unroll
    for (int k = 0; k < 32; ++k) v[k] = 0.f;

    CHUNK(d0)
    CHUNK(d1)

    // ---- Compaction butterfly: 31 swizzles + 1 xor32 (R5-proven) ----
    { const bool hi_ = (lane & 1) != 0;
      SHIP(0,16,1)  SHIP(1,16,1)  SHIP(2,16,1)  SHIP(3,16,1)
      SHIP(4,16,1)  SHIP(5,16,1)  SHIP(6,16,1)  SHIP(7,16,1)
      SHIP(8,16,1)  SHIP(9,16,1)  SHIP(10,16,1) SHIP(11,16,1)
      SHIP(12,16,1) SHIP(13,16,1) SHIP(14,16,1) SHIP(15,16,1) }
    { const bool hi_ = (lane & 2) != 0;
      SHIP(0,8,2) SHIP(1,8,2) SHIP(2,8,2) SHIP(3,8,2)
      SHIP(4,8,2) SHIP(5,8,2) SHIP(6,8,2) SHIP(7,8,2) }
    { const bool hi_ = (lane & 4) != 0;
      SHIP(0,4,4) SHIP(1,4,4) SHIP(2,4,4) SHIP(3,4,4) }
    { const bool hi_ = (lane & 8) != 0;
      SHIP(0,2,8) SHIP(1,2,8) }
    { const bool hi_ = (lane & 16) != 0;
      SHIP(0,1,16) }
    const float tot = v[0] + __shfl_xor(v[0], 32);
    const int idx = ((lane & 1) << 4) | ((lane & 2) << 2) | (lane & 4)
                  | ((lane & 8) >> 2) | ((lane & 16) >> 4);   // brev5(lane&31)
    if (lane < 32) red[wave][idx] = tot;
    __syncthreads();

    // ---- 24 threads: one tanh each (R5-proven epilogue) ----
    if (tid < 24) {
        const int s = tid / 6;
        const int j = tid % 6;
        const float ssq = red[0][s * 7] + red[1][s * 7] + red[2][s * 7] + red[3][s * 7];
        const float dot = red[0][s * 7 + 1 + j] + red[1][s * 7 + 1 + j]
                        + red[2][s * 7 + 1 + j] + red[3][s * 7 + 1 + j];
        const float rs  = SQRT_D / fmaxf(sqrtf(ssq), 1e-12f);
        const float th  = tanhf(dot * rs);
        asb[s][j] = (j < 5) ? (th * scale_alpha[0] + static_alpha[s * 5 + j])
                            : (th * scale_beta[0]  + static_beta[s]);
    }
    __syncthreads();

    // ---- M[so][si] = beta[so]*alpha[si][0] + alpha[si][so+1] (broadcast reads) ----
    float M[NS][NS];
#pragma unroll
    for (int so = 0; so < NS; ++so)
#pragma unroll
        for (int si = 0; si < NS; ++si)
            M[so][si] = asb[so][5] * asb[si][0] + asb[si][so + 1];

    // ---- Apply from bf16 LDS copy: out[so][d] = sum_si M[so][si]*x[si][d] ----
    float* obase = out + (size_t)(b * NS) * row_stride + (size_t)n * ND;
#pragma unroll
    for (int c = 0; c < 2; ++c) {
        const int d = (c == 0) ? d0 : d1;
        uint2 q0 = *(uint2*)&lds_h[0 * ND + d];
        uint2 q1 = *(uint2*)&lds_h[1 * ND + d];
        uint2 q2 = *(uint2*)&lds_h[2 * ND + d];
        uint2 q3 = *(uint2*)&lds_h[3 * ND + d];
        f32x4 xs0 = {bflo(q0.x), bfhi(q0.x), bflo(q0.y), bfhi(q0.y)};
        f32x4 xs1 = {bflo(q1.x), bfhi(q1.x), bflo(q1.y), bfhi(q1.y)};
        f32x4 xs2 = {bflo(q2.x), bfhi(q2.x), bflo(q2.y), bfhi(q2.y)};
        f32x4 xs3 = {bflo(q3.x), bfhi(q3.x), bflo(q3.y), bfhi(q3.y)};
#pragma unroll
        for (int so = 0; so < NS; ++so) {
            f32x4 o;
#pragma unroll
            for (int e = 0; e < 4; ++e)
                o[e] = M[so][0] * xs0[e] + M[so][1] * xs1[e]
                     + M[so][2] * xs2[e] + M[so][3] * xs3[e];
            __builtin_nontemporal_store(o, (f32x4*)(obase + (size_t)so * row_stride + d));
        }
    }
}

extern "C" void kernel_launch(void* const* d_in, const int* in_sizes, int n_in,
                              void* d_out, int out_size, void* d_ws, size_t ws_size,
                              hipStream_t stream) {
    const float* residuals    = (const float*)d_in[0];
    const float* gamma        = (const float*)d_in[1];
    const float* w_alpha      = (const float*)d_in[2];
    const float* scale_alpha  = (const float*)d_in[3];
    const float* static_alpha = (const float*)d_in[4];
    const float* w_beta       = (const float*)d_in[5];
    const float* scale_beta   = (const float*)d_in[6];
    const float* static_beta  = (const float*)d_in[7];
    float* out = (float*)d_out;

    const int grid = NB * NN;  // 8192 blocks, one per (b, n)
    hyperconn_kernel<<<grid, NTHREADS, 0, stream>>>(
        residuals, gamma, w_alpha, scale_alpha, static_alpha,
        w_beta, scale_beta, static_beta, out);
}